// Round 12
// baseline (830.016 us; speedup 1.0000x reference)
//
#include <hip/hip_runtime.h>
#include <hip/hip_bf16.h>

// out = data @ (mask*weight)^T + bias, via bf16 MFMA.
// Round 12: LDS-traffic route. 256x256 block, FOUR waves of 128x128 output
// (0.0156 LDS-B/FLOP, -33% vs R4's 8-wave 128x64), BK=32, ring-3 LDS (96KB),
// 1 wave/SIMD (~410 VGPR), all-tile-ahead ds_read prefetch keeps the LDS
// queue fed under the MFMA cluster. R4's zero-conflict swizzle throughout.

#define GM 8192
#define GN 4096
#define GK 4096
#define NT (GK / 32)   // 128 K-tiles of BK=32

typedef __attribute__((ext_vector_type(8))) short short8;
typedef __attribute__((ext_vector_type(8))) short bf16x8;
typedef __attribute__((ext_vector_type(4))) float f32x4;

__device__ __forceinline__ short f2bf(float x) {
    unsigned u = __builtin_bit_cast(unsigned, x);
    u += 0x7fffu + ((u >> 16) & 1u);
    return (short)(u >> 16);
}

__device__ __forceinline__ void stage16(const short* g, short* l) {
    __builtin_amdgcn_global_load_lds(
        (const __attribute__((address_space(1))) unsigned int*)g,
        (__attribute__((address_space(3))) unsigned int*)l, 16, 0, 0);
}

// --- conversion: data f32 -> bf16 ---
__global__ void cvt_data_kernel(const float* __restrict__ in, short* __restrict__ out, long n) {
    long i0 = ((long)blockIdx.x * blockDim.x + threadIdx.x) * 8;
    long stride = (long)gridDim.x * blockDim.x * 8;
    for (long i = i0; i < n; i += stride) {
        float4 a = *(const float4*)(in + i);
        float4 b = *(const float4*)(in + i + 4);
        short8 o;
        o[0] = f2bf(a.x); o[1] = f2bf(a.y); o[2] = f2bf(a.z); o[3] = f2bf(a.w);
        o[4] = f2bf(b.x); o[5] = f2bf(b.y); o[6] = f2bf(b.z); o[7] = f2bf(b.w);
        *(short8*)(out + i) = o;
    }
}

// --- conversion: (mask * weight) f32 -> bf16 ---
__global__ void cvt_w_kernel(const float* __restrict__ w, const float* __restrict__ m,
                             short* __restrict__ out, long n) {
    long i0 = ((long)blockIdx.x * blockDim.x + threadIdx.x) * 8;
    long stride = (long)gridDim.x * blockDim.x * 8;
    for (long i = i0; i < n; i += stride) {
        float4 wa = *(const float4*)(w + i);
        float4 wb = *(const float4*)(w + i + 4);
        float4 ma = *(const float4*)(m + i);
        float4 mb = *(const float4*)(m + i + 4);
        short8 o;
        o[0] = f2bf(wa.x * ma.x); o[1] = f2bf(wa.y * ma.y);
        o[2] = f2bf(wa.z * ma.z); o[3] = f2bf(wa.w * ma.w);
        o[4] = f2bf(wb.x * mb.x); o[5] = f2bf(wb.y * mb.y);
        o[6] = f2bf(wb.z * mb.z); o[7] = f2bf(wb.w * mb.w);
        *(short8*)(out + i) = o;
    }
}

// --- 4-wave big-tile bf16 NT GEMM ---
// LDS (shorts): slot s (0..2) at s*16384 (32KB): A [256r][32c] +0, B [256r][32c]
// +8192. 64B rows, quarter-swizzle stored q = logical q ^
// ((((row>>3)&1)<<1)|((row>>1)&1))  (R4's measured-zero-conflict pattern).
//
// Per tile T: { stage T+2 -> slot (T+2)%3 (8 gload_lds, 256 threads);
//   vmcnt(8) confirms T+1 (issued one full tile ago); barrier;
//   issue 16 ds_reads of tile T+1 (slot (T+1)%3) -> NXT frag set (no consumer
//   this tile -> no lgkm wait, drains under MFMA); sched_barrier;
//   64 MFMA on CUR frag set (compiler counted-lgkm) }.
// WAR: stage(T+2) writes slot (T-1)%3, last read by ds_reads issued in tile
// T-2 and consumed before tile T-1's end; >=1 barrier + full MFMA separation.
__global__ __launch_bounds__(256, 1) void gemm_4w(const short* __restrict__ A,
                                                  const short* __restrict__ B,
                                                  const float* __restrict__ bias,
                                                  float* __restrict__ C) {
    __shared__ short lds[49152];  // 96 KB = 3 slots x 16384 shorts

    const int tid  = threadIdx.x;
    const int lane = tid & 63;
    const int wid  = tid >> 6;   // 0..3
    const int wr   = wid >> 1;   // 0..1  (wave row: 128 rows)
    const int wc   = wid & 1;    // 0..1  (wave col: 128 cols)

    // XCD-aware bijective swizzle: nwg = 512, % 8 == 0
    const int bid  = blockIdx.x;
    const int swz  = (bid & 7) * 64 + (bid >> 3);
    const int brow = (swz >> 4) << 8;   // 32 M-tiles
    const int bcol = (swz & 15) << 8;   // 16 N-tiles

    // ---- staging constants (pre-swizzled global source; linear LDS dest) ----
    const int trow = tid >> 2;          // 0..63 row within 64-row line
    const int qlog = (tid & 3) ^ ((((trow >> 3) & 1) << 1) | ((trow >> 1) & 1));

    // ---- fragment-read constants (swizzled LDS read) ----
    const int l15 = lane & 15;
    const int q   = lane >> 4;
    const int qx  = (((l15 >> 3) & 1) << 1) | ((l15 >> 1) & 1);
    const int foff = l15 * 32 + ((q ^ qx) << 3);   // shorts
    const int aOff = wr * 4096 + foff;             // + slot + m*512
    const int bOff = 8192 + wc * 4096 + foff;      // + slot + n*512

    f32x4 acc[8][8] = {};
    bf16x8 afA[8], bfA[8], afB[8], bfB[8];   // even-tile / odd-tile frag sets

    auto stage = [&](int sb, size_t kcol) {
        #pragma unroll
        for (int j = 0; j < 4; ++j)
            stage16(A + (size_t)(brow + j * 64 + trow) * GK + kcol + qlog * 8,
                    &lds[sb + j * 2048 + wid * 512]);
        #pragma unroll
        for (int j = 0; j < 4; ++j)
            stage16(B + (size_t)(bcol + j * 64 + trow) * GK + kcol + qlog * 8,
                    &lds[sb + 8192 + j * 2048 + wid * 512]);
    };

    // ---- prologue: stage tiles 0,1; confirm 0; read tile-0 frags ----
    stage(0, 0);
    stage(16384, 32);
    asm volatile("s_waitcnt vmcnt(8)" ::: "memory");
    __builtin_amdgcn_s_barrier();
    asm volatile("" ::: "memory");
    #pragma unroll
    for (int m = 0; m < 8; ++m) afA[m] = *(const bf16x8*)&lds[aOff + m * 512];
    #pragma unroll
    for (int n = 0; n < 8; ++n) bfA[n] = *(const bf16x8*)&lds[bOff + n * 512];

#define BODY(T, CA, CB, NA, NB)                                                    \
  {                                                                                 \
    const bool stg = (T) + 2 < NT;                                                  \
    if (stg) stage((((T) + 2) % 3) * 16384, (size_t)((T) + 2) * 32);                \
    if (stg) { asm volatile("s_waitcnt vmcnt(8)" ::: "memory"); }                   \
    else     { asm volatile("s_waitcnt vmcnt(0)" ::: "memory"); }                   \
    __builtin_amdgcn_s_barrier();                                                   \
    asm volatile("" ::: "memory");                                                  \
    if ((T) + 1 < NT) {                                                             \
      const int ns = (((T) + 1) % 3) * 16384;                                       \
      _Pragma("unroll")                                                             \
      for (int m = 0; m < 8; ++m) NA[m] = *(const bf16x8*)&lds[ns + aOff + m * 512];\
      _Pragma("unroll")                                                             \
      for (int n = 0; n < 8; ++n) NB[n] = *(const bf16x8*)&lds[ns + bOff + n * 512];\
    }                                                                               \
    __builtin_amdgcn_sched_barrier(0);                                              \
    _Pragma("unroll")                                                               \
    for (int m = 0; m < 8; ++m)                                                     \
      _Pragma("unroll")                                                             \
      for (int n = 0; n < 8; ++n)                                                   \
        acc[m][n] = __builtin_amdgcn_mfma_f32_16x16x32_bf16(CA[m], CB[n],           \
                                                            acc[m][n], 0, 0, 0);    \
  }

    for (int T = 0; T < NT; T += 2) {
        BODY(T,     afA, bfA, afB, bfB)
        BODY(T + 1, afB, bfB, afA, bfA)
    }
#undef BODY

    // ---- epilogue: C/D layout col = lane&15, row = (lane>>4)*4 + r ----
    #pragma unroll
    for (int n = 0; n < 8; ++n) {
        const int col = bcol + wc * 128 + n * 16 + l15;
        const float bv = bias[col];
        #pragma unroll
        for (int m = 0; m < 8; ++m) {
            const int rowb = brow + wr * 128 + m * 16 + (q << 2);
            #pragma unroll
            for (int r = 0; r < 4; ++r)
                C[(size_t)(rowb + r) * GN + col] = acc[m][n][r] + bv;
        }
    }
}

extern "C" void kernel_launch(void* const* d_in, const int* in_sizes, int n_in,
                              void* d_out, int out_size, void* d_ws, size_t ws_size,
                              hipStream_t stream) {
    const float* data   = (const float*)d_in[0];  // [8192,4096]
    const float* weight = (const float*)d_in[1];  // [4096,4096]
    const float* mask   = (const float*)d_in[2];  // [4096,4096]
    const float* bias   = (const float*)d_in[3];  // [4096]
    float* out = (float*)d_out;

    short* dataB = (short*)d_ws;                  // 64 MB bf16 data
    short* wB    = dataB + (size_t)GM * GK;       // 32 MB bf16 masked weight

    cvt_data_kernel<<<2048, 256, 0, stream>>>(data, dataB, (long)GM * GK);
    cvt_w_kernel<<<2048, 256, 0, stream>>>(weight, mask, wB, (long)GN * GK);

    // grid = (8192/256) * (4096/256) = 32 * 16 = 512 workgroups, 4 waves each
    gemm_4w<<<512, 256, 0, stream>>>(dataB, wB, bias, out);
}